// Round 1
// baseline (3219.418 us; speedup 1.0000x reference)
//
#include <hip/hip_runtime.h>
#include <math.h>

#define N_ROWS 32768
#define DIM 256
#define K_CODES 1024

// ---- workspace float offsets (total ~1.2 MB) ----
#define WS_LOSS   0        // 1024 distributed loss slots
#define WS_NSUM   1024
#define WS_ZZ     2048     // 32768
#define WS_EE     34816    // 1024
#define WS_COUNTS 35840    // 1024
#define WS_ESUM   36864    // 1024*256
#define WS_TOTAL  (36864 + K_CODES * DIM)   // 299008 floats

// ---- output float offsets (return-order concatenation) ----
#define OFF_ZQ    0ull
#define OFF_CODES 8388608ull
#define OFF_LOSS  8421376ull
#define OFF_PERP  8421377ull
#define OFF_ENT   8421378ull
#define OFF_SOFT  8421379ull          // %4==3 -> scalar access in this region
#define OFF_NEMB  41975811ull
#define OFF_NCS   42237955ull
#define OFF_NEA   42238979ull

__global__ __launch_bounds__(256) void k0_zero(float* ws) {
    int i = blockIdx.x * 256 + threadIdx.x;
    if (i < WS_TOTAL) ws[i] = 0.0f;
}

// one wave per row: zz[n]=||z_n||^2 for rows < N_ROWS, ee[k]=||e_k||^2 otherwise
__global__ __launch_bounds__(256) void k1_norms(const float* __restrict__ z,
                                                const float* __restrict__ embed,
                                                float* __restrict__ ws) {
    int wave = threadIdx.x >> 6;
    int lane = threadIdx.x & 63;
    int row = blockIdx.x * 4 + wave;
    const float* src = (row < N_ROWS) ? (z + (size_t)row * DIM)
                                      : (embed + (size_t)(row - N_ROWS) * DIM);
    float4 v = *(const float4*)(src + lane * 4);
    float s = v.x * v.x + v.y * v.y + v.z * v.z + v.w * v.w;
    #pragma unroll
    for (int off = 32; off; off >>= 1) s += __shfl_down(s, off, 64);
    if (lane == 0) {
        if (row < N_ROWS) ws[WS_ZZ + row] = s;
        else              ws[WS_EE + (row - N_ROWS)] = s;
    }
}

// Fused dist-GEMM + argmin + softmax + z_q + loss + EMA scatter.
// Block = 1024 threads, tile = 64 rows x 1024 (ALL) cols, so every row's full
// K extent is register-resident and the 128 MB dist round-trip disappears.
// Thread t: rowgroup rg=t>>7 (8 rows rg*8+i), colgroup c=t&127 (8 cols c+128*j).
// FMA order (d = 0..255 sequential) and (zz - 2*acc) + ee match old k2 exactly
// -> dist values bit-identical to the previously verified kernel.
__global__ __launch_bounds__(1024) void k23_fused(const float* __restrict__ z,
                                                  const float* __restrict__ embed,
                                                  float* __restrict__ ws,
                                                  float* __restrict__ out) {
    __shared__ float sB[16][1024];   // embed^T tile: sB[d][code]
    __shared__ float sA[16][64];     // z^T tile: sA[d][row]
    __shared__ float red [8][8][2];  // [rg][i][wave-in-pair] reduce scratch
    __shared__ int   redi[8][8][2];
    __shared__ float rowmin[64];
    __shared__ int   rowcode[64];
    __shared__ float rowsum[64];
    __shared__ int   rownc[64];
    __shared__ int   rowcand[64][8];
    __shared__ double sdd[16];
    __shared__ int   anytie;

    int tid  = threadIdx.x;
    int lane = tid & 63;
    int rg   = tid >> 7;          // 0..7
    int c    = tid & 127;         // 0..127
    int wid2 = (tid >> 6) & 1;    // which wave of the 2-wave rowgroup
    int rowBase = blockIdx.x * 64;
    int base_r  = rg * 8;

    float acc[8][8];
    #pragma unroll
    for (int i = 0; i < 8; ++i)
        #pragma unroll
        for (int j = 0; j < 8; ++j) acc[i][j] = 0.f;

    // ---------------- GEMM: acc[i][j] = z_row . e_col over D=256 ----------------
    for (int dt = 0; dt < 16; ++dt) {
        int d0 = dt * 16;
        __syncthreads();
        // stage B (transpose embed[code][d] -> sB[d][code]); L2-resident source
        #pragma unroll
        for (int it = 0; it < 4; ++it) {
            int g = it * 1024 + tid;             // 0..4095
            int code = g >> 2, chunk = g & 3;    // 4 float4 chunks per code
            float4 v = *(const float4*)&embed[(size_t)code * DIM + d0 + chunk * 4];
            sB[chunk * 4 + 0][code] = v.x; sB[chunk * 4 + 1][code] = v.y;
            sB[chunk * 4 + 2][code] = v.z; sB[chunk * 4 + 3][code] = v.w;
        }
        // stage A (transpose z)
        if (tid < 256) {
            int row = tid >> 2, chunk = tid & 3;
            float4 v = *(const float4*)&z[(size_t)(rowBase + row) * DIM + d0 + chunk * 4];
            sA[chunk * 4 + 0][row] = v.x; sA[chunk * 4 + 1][row] = v.y;
            sA[chunk * 4 + 2][row] = v.z; sA[chunk * 4 + 3][row] = v.w;
        }
        __syncthreads();
        #pragma unroll
        for (int d = 0; d < 16; ++d) {
            float4 a0 = *(const float4*)&sA[d][rg * 8];       // wave-uniform: broadcast
            float4 a1 = *(const float4*)&sA[d][rg * 8 + 4];
            float av[8] = {a0.x, a0.y, a0.z, a0.w, a1.x, a1.y, a1.z, a1.w};
            float bv[8];
            #pragma unroll
            for (int j = 0; j < 8; ++j) bv[j] = sB[d][c + 128 * j];  // 2-way alias: free
            #pragma unroll
            for (int i = 0; i < 8; ++i)
                #pragma unroll
                for (int j = 0; j < 8; ++j) acc[i][j] += av[i] * bv[j];
        }
    }

    // ---------------- dist in registers (identical expression to old k2) --------
    float zzv[8], eev[8];
    #pragma unroll
    for (int i = 0; i < 8; ++i) zzv[i] = ws[WS_ZZ + rowBase + base_r + i];
    #pragma unroll
    for (int j = 0; j < 8; ++j) eev[j] = ws[WS_EE + c + 128 * j];
    #pragma unroll
    for (int i = 0; i < 8; ++i)
        #pragma unroll
        for (int j = 0; j < 8; ++j) acc[i][j] = (zzv[i] - 2.0f * acc[i][j]) + eev[j];

    // ---------------- per-row argmin (lowest-k tiebreak) ------------------------
    #pragma unroll
    for (int i = 0; i < 8; ++i) {
        float v = acc[i][0]; int idx = c;        // j ascending => k ascending
        #pragma unroll
        for (int j = 1; j < 8; ++j) {
            if (acc[i][j] < v) { v = acc[i][j]; idx = c + 128 * j; }
        }
        #pragma unroll
        for (int off = 32; off; off >>= 1) {
            float ov = __shfl_down(v, off, 64);
            int   oi = __shfl_down(idx, off, 64);
            if (ov < v || (ov == v && oi < idx)) { v = ov; idx = oi; }
        }
        if (lane == 0) { red[rg][i][wid2] = v; redi[rg][i][wid2] = idx; }
    }
    if (tid == 0) anytie = 0;
    if (tid < 64) rownc[tid] = 0;
    __syncthreads();
    if (tid < 64) {
        float v0 = red[tid >> 3][tid & 7][0]; int i0 = redi[tid >> 3][tid & 7][0];
        float v1 = red[tid >> 3][tid & 7][1]; int i1 = redi[tid >> 3][tid & 7][1];
        if (v1 < v0 || (v1 == v0 && i1 < i0)) { v0 = v1; i0 = i1; }
        rowmin[tid] = v0; rowcode[tid] = i0;
    }
    __syncthreads();

    // ---------------- near-tie candidates (1e-3 band >> fp32 dist error) --------
    #pragma unroll
    for (int i = 0; i < 8; ++i) {
        int r = base_r + i;
        float thr = rowmin[r] + 1e-3f;
        #pragma unroll
        for (int j = 0; j < 8; ++j) {
            if (acc[i][j] <= thr) {
                int slot = atomicAdd(&rownc[r], 1);
                if (slot < 8) rowcand[r][slot] = c + 128 * j;
            }
        }
    }
    __syncthreads();
    if (tid < 64 && rownc[tid] > 1) atomicAdd(&anytie, 1);
    __syncthreads();
    if (anytie) {    // rare path: fp64 re-dot, numpy-style fp32 final rounding
        for (int r = 0; r < 64; ++r) {
            int nc = rownc[r];
            if (nc <= 1) continue;
            int lim = nc < 8 ? nc : 8;
            int n = rowBase + r;
            float zzn = ws[WS_ZZ + n];
            float bestd = 0.f; int bestk = -1;
            for (int ci = 0; ci < lim; ++ci) {
                int kc = rowcand[r][ci];
                double part = 0.0;
                if (tid < 256)
                    part = (double)z[(size_t)n * DIM + tid] * (double)embed[(size_t)kc * DIM + tid];
                #pragma unroll
                for (int off = 32; off; off >>= 1) part += __shfl_down(part, off, 64);
                if (lane == 0) sdd[tid >> 6] = part;
                __syncthreads();
                double dot = 0.0;
                for (int w = 0; w < 16; ++w) dot += sdd[w];
                float d32 = (zzn - 2.0f * (float)dot) + ws[WS_EE + kc];
                if (bestk < 0 || d32 < bestd || (d32 == bestd && kc < bestk)) { bestd = d32; bestk = kc; }
                __syncthreads();     // protect sdd reuse
            }
            if (tid == 0) rowcode[r] = bestk;
        }
        __syncthreads();
    }

    // ---------------- softmax (shift by rowmin is exact-invariant) --------------
    #pragma unroll
    for (int i = 0; i < 8; ++i) {
        float m = rowmin[base_r + i];
        float s = 0.f;
        #pragma unroll
        for (int j = 0; j < 8; ++j) {
            acc[i][j] = __expf((m - acc[i][j]) * 10.0f);
            s += acc[i][j];
        }
        #pragma unroll
        for (int off = 32; off; off >>= 1) s += __shfl_down(s, off, 64);
        if (lane == 0) red[rg][i][wid2] = s;
    }
    __syncthreads();
    if (tid < 64) rowsum[tid] = red[tid >> 3][tid & 7][0] + red[tid >> 3][tid & 7][1];
    __syncthreads();
    #pragma unroll
    for (int i = 0; i < 8; ++i) {
        int n = rowBase + base_r + i;
        float inv = 1.0f / rowsum[base_r + i];
        float* orow = out + OFF_SOFT + (size_t)n * K_CODES;
        #pragma unroll
        for (int j = 0; j < 8; ++j) orow[c + 128 * j] = acc[i][j] * inv;  // lane-coalesced
    }

    // ---------------- z_q, commitment loss, EMA scatter -------------------------
    {
        int r   = tid >> 4;          // 0..63
        int seg = tid & 15;          // 16 threads/row, 16 d each
        int n = rowBase + r;
        int code = rowcode[r];
        int dd = seg * 16;
        float lsum = 0.f;
        #pragma unroll
        for (int q = 0; q < 4; ++q) {
            float4 e4 = *(const float4*)&embed[(size_t)code * DIM + dd + q * 4];
            float4 z4 = *(const float4*)&z[(size_t)n * DIM + dd + q * 4];
            *(float4*)&out[OFF_ZQ + (size_t)n * DIM + dd + q * 4] = e4;
            float dx = z4.x - e4.x, dy = z4.y - e4.y, dz_ = z4.z - e4.z, dw = z4.w - e4.w;
            lsum += dx * dx + dy * dy + dz_ * dz_ + dw * dw;
            atomicAdd(&ws[WS_ESUM + (size_t)code * DIM + dd + q * 4 + 0], z4.x);
            atomicAdd(&ws[WS_ESUM + (size_t)code * DIM + dd + q * 4 + 1], z4.y);
            atomicAdd(&ws[WS_ESUM + (size_t)code * DIM + dd + q * 4 + 2], z4.z);
            atomicAdd(&ws[WS_ESUM + (size_t)code * DIM + dd + q * 4 + 3], z4.w);
        }
        #pragma unroll
        for (int off = 8; off; off >>= 1) lsum += __shfl_down(lsum, off, 16);
        if (seg == 0) {
            atomicAdd(&ws[WS_LOSS + (n & 1023)], lsum);   // 1024-way distributed
            atomicAdd(&ws[WS_COUNTS + code], 1.0f);
            out[OFF_CODES + n] = (float)code;
        }
    }
}

__global__ __launch_bounds__(1024) void k4a_stats(const float* __restrict__ cluster_size,
                                                  float* __restrict__ ws,
                                                  float* __restrict__ out) {
    __shared__ float sm[16];
    int k = threadIdx.x;
    int lane = k & 63, wave = k >> 6;
    float cnt = ws[WS_COUNTS + k];
    float ncs = 0.99f * cluster_size[k] + 0.01f * cnt;
    out[OFF_NCS + k] = ncs;

    // nsum
    float v = ncs;
    #pragma unroll
    for (int off = 32; off; off >>= 1) v += __shfl_down(v, off, 64);
    if (lane == 0) sm[wave] = v;
    __syncthreads();
    if (k == 0) {
        float t = 0.f;
        for (int w = 0; w < 16; ++w) t += sm[w];
        ws[WS_NSUM] = t;
    }
    __syncthreads();

    // entropy
    float avg = cnt / (float)N_ROWS;
    v = -avg * logf(avg + 1e-10f);
    #pragma unroll
    for (int off = 32; off; off >>= 1) v += __shfl_down(v, off, 64);
    if (lane == 0) sm[wave] = v;
    __syncthreads();
    if (k == 0) {
        float ent = 0.f;
        for (int w = 0; w < 16; ++w) ent += sm[w];
        out[OFF_ENT]  = ent;
        out[OFF_PERP] = expf(ent);
    }
    __syncthreads();

    // loss: sum the 1024 distributed slots
    v = ws[WS_LOSS + k];
    #pragma unroll
    for (int off = 32; off; off >>= 1) v += __shfl_down(v, off, 64);
    if (lane == 0) sm[wave] = v;
    __syncthreads();
    if (k == 0) {
        float t = 0.f;
        for (int w = 0; w < 16; ++w) t += sm[w];
        out[OFF_LOSS] = t / 8388608.0f;
    }
}

__global__ __launch_bounds__(256) void k4b_embed(const float* __restrict__ embed_avg,
                                                 const float* __restrict__ ws,
                                                 float* __restrict__ out) {
    int k = blockIdx.x, d = threadIdx.x;
    float es  = ws[WS_ESUM + (size_t)k * DIM + d];
    float nea = 0.99f * embed_avg[(size_t)k * DIM + d] + 0.01f * es;
    out[OFF_NEA + (size_t)k * DIM + d] = nea;
    float ncs  = out[OFF_NCS + k];
    float nsum = ws[WS_NSUM];
    float csn  = (ncs + 1e-5f) / (nsum + K_CODES * 1e-5f) * nsum;
    out[OFF_NEMB + (size_t)k * DIM + d] = nea / csn;
}

extern "C" void kernel_launch(void* const* d_in, const int* in_sizes, int n_in,
                              void* d_out, int out_size, void* d_ws, size_t ws_size,
                              hipStream_t stream) {
    const float* z            = (const float*)d_in[0];
    const float* embed        = (const float*)d_in[1];
    const float* cluster_size = (const float*)d_in[2];
    const float* embed_avg    = (const float*)d_in[3];
    float* out = (float*)d_out;
    float* ws  = (float*)d_ws;

    k0_zero<<<(WS_TOTAL + 255) / 256, 256, 0, stream>>>(ws);
    k1_norms<<<(N_ROWS + K_CODES) / 4, 256, 0, stream>>>(z, embed, ws);
    k23_fused<<<N_ROWS / 64, 1024, 0, stream>>>(z, embed, ws, out);
    k4a_stats<<<1, 1024, 0, stream>>>(cluster_size, ws, out);
    k4b_embed<<<K_CODES, 256, 0, stream>>>(embed_avg, ws, out);
}

// Round 2
// 866.749 us; speedup vs baseline: 3.7144x; 3.7144x over previous
//
#include <hip/hip_runtime.h>
#include <math.h>

#define N_ROWS 32768
#define DIM 256
#define K_CODES 1024

// ---- workspace float offsets (total ~1.2 MB) ----
#define WS_LOSS   0        // 1024 distributed loss slots
#define WS_NSUM   1024
#define WS_ZZ     2048     // 32768
#define WS_EE     34816    // 1024
#define WS_COUNTS 35840    // 1024
#define WS_ESUM   36864    // 1024*256
#define WS_TOTAL  (36864 + K_CODES * DIM)   // 299008 floats

// ---- output float offsets (return-order concatenation) ----
#define OFF_ZQ    0ull
#define OFF_CODES 8388608ull
#define OFF_LOSS  8421376ull
#define OFF_PERP  8421377ull
#define OFF_ENT   8421378ull
#define OFF_SOFT  8421379ull          // %4==3 -> scalar access in this region
#define OFF_NEMB  41975811ull
#define OFF_NCS   42237955ull
#define OFF_NEA   42238979ull

__global__ __launch_bounds__(256) void k0_zero(float* ws) {
    int i = blockIdx.x * 256 + threadIdx.x;
    if (i < WS_TOTAL) ws[i] = 0.0f;
}

// one wave per row: zz[n]=||z_n||^2 for rows < N_ROWS, ee[k]=||e_k||^2 otherwise
__global__ __launch_bounds__(256) void k1_norms(const float* __restrict__ z,
                                                const float* __restrict__ embed,
                                                float* __restrict__ ws) {
    int wave = threadIdx.x >> 6;
    int lane = threadIdx.x & 63;
    int row = blockIdx.x * 4 + wave;
    const float* src = (row < N_ROWS) ? (z + (size_t)row * DIM)
                                      : (embed + (size_t)(row - N_ROWS) * DIM);
    float4 v = *(const float4*)(src + lane * 4);
    float s = v.x * v.x + v.y * v.y + v.z * v.z + v.w * v.w;
    #pragma unroll
    for (int off = 32; off; off >>= 1) s += __shfl_down(s, off, 64);
    if (lane == 0) {
        if (row < N_ROWS) ws[WS_ZZ + row] = s;
        else              ws[WS_EE + (row - N_ROWS)] = s;
    }
}

// Fused dist-GEMM + argmin + softmax + z_q + loss + EMA scatter.
// R2 fix vs R1: 512 threads (8 waves), 32 rows x 1024 cols tile, and
// __launch_bounds__(512, 2) -> VGPR cap 256 (1 block/CU min), so the 64
// accumulators stay in registers (R1's 1024-thread version capped at 64 VGPR
// and spilled 11.5 GB of scratch to HBM).
// Thread t: rowgroup rg=t>>7 (8 rows rg*8+i), colgroup c=t&127 (8 cols c+128*j).
// FMA order (d = 0..255 sequential) and (zz - 2*acc) + ee match the verified
// kernels exactly -> dist values bit-identical.
__global__ __launch_bounds__(512, 2) void k23_fused(const float* __restrict__ z,
                                                    const float* __restrict__ embed,
                                                    float* __restrict__ ws,
                                                    float* __restrict__ out) {
    __shared__ float sB[8][1024];    // embed^T tile: sB[d][code]  (32 KB)
    __shared__ float sA[8][32];      // z^T tile: sA[d][row]
    __shared__ float red [4][8][2];  // [rg][i][wave-in-pair] reduce scratch
    __shared__ int   redi[4][8][2];
    __shared__ float rowmin[32];
    __shared__ int   rowcode[32];
    __shared__ float rowsum[32];
    __shared__ int   rownc[32];
    __shared__ int   rowcand[32][8];
    __shared__ double sdd[8];
    __shared__ int   anytie;

    int tid  = threadIdx.x;
    int lane = tid & 63;
    int wid  = tid >> 6;          // 0..7
    int rg   = tid >> 7;          // 0..3
    int c    = tid & 127;         // 0..127
    int wid2 = wid & 1;           // which wave of the 2-wave rowgroup
    int rowBase = blockIdx.x * 32;
    int base_r  = rg * 8;

    float acc[8][8];
    #pragma unroll
    for (int i = 0; i < 8; ++i)
        #pragma unroll
        for (int j = 0; j < 8; ++j) acc[i][j] = 0.f;

    // ---------------- GEMM: acc[i][j] = z_row . e_col over D=256 ----------------
    for (int dt = 0; dt < 32; ++dt) {
        int d0 = dt * 8;
        __syncthreads();
        // stage B (transpose embed[code][d] -> sB[d][code]); L2-resident source
        #pragma unroll
        for (int it = 0; it < 4; ++it) {
            int g = it * 512 + tid;              // 0..2047
            int code = g >> 1, chunk = g & 1;    // 2 float4 chunks per code (8 d's)
            float4 v = *(const float4*)&embed[(size_t)code * DIM + d0 + chunk * 4];
            sB[chunk * 4 + 0][code] = v.x; sB[chunk * 4 + 1][code] = v.y;
            sB[chunk * 4 + 2][code] = v.z; sB[chunk * 4 + 3][code] = v.w;
        }
        // stage A (transpose z): 32 rows x 8 d = 64 float4
        if (tid < 64) {
            int row = tid >> 1, chunk = tid & 1;
            float4 v = *(const float4*)&z[(size_t)(rowBase + row) * DIM + d0 + chunk * 4];
            sA[chunk * 4 + 0][row] = v.x; sA[chunk * 4 + 1][row] = v.y;
            sA[chunk * 4 + 2][row] = v.z; sA[chunk * 4 + 3][row] = v.w;
        }
        __syncthreads();
        #pragma unroll
        for (int d = 0; d < 8; ++d) {
            float4 a0 = *(const float4*)&sA[d][rg * 8];       // wave-uniform: broadcast
            float4 a1 = *(const float4*)&sA[d][rg * 8 + 4];
            float av[8] = {a0.x, a0.y, a0.z, a0.w, a1.x, a1.y, a1.z, a1.w};
            float bv[8];
            #pragma unroll
            for (int j = 0; j < 8; ++j) bv[j] = sB[d][c + 128 * j];  // 2-way alias: free
            #pragma unroll
            for (int i = 0; i < 8; ++i)
                #pragma unroll
                for (int j = 0; j < 8; ++j) acc[i][j] += av[i] * bv[j];
        }
    }

    // ---------------- dist in registers (identical expression to old k2) --------
    float zzv[8], eev[8];
    #pragma unroll
    for (int i = 0; i < 8; ++i) zzv[i] = ws[WS_ZZ + rowBase + base_r + i];
    #pragma unroll
    for (int j = 0; j < 8; ++j) eev[j] = ws[WS_EE + c + 128 * j];
    #pragma unroll
    for (int i = 0; i < 8; ++i)
        #pragma unroll
        for (int j = 0; j < 8; ++j) acc[i][j] = (zzv[i] - 2.0f * acc[i][j]) + eev[j];

    // ---------------- per-row argmin (lowest-k tiebreak) ------------------------
    #pragma unroll
    for (int i = 0; i < 8; ++i) {
        float v = acc[i][0]; int idx = c;        // j ascending => k ascending
        #pragma unroll
        for (int j = 1; j < 8; ++j) {
            if (acc[i][j] < v) { v = acc[i][j]; idx = c + 128 * j; }
        }
        #pragma unroll
        for (int off = 32; off; off >>= 1) {
            float ov = __shfl_down(v, off, 64);
            int   oi = __shfl_down(idx, off, 64);
            if (ov < v || (ov == v && oi < idx)) { v = ov; idx = oi; }
        }
        if (lane == 0) { red[rg][i][wid2] = v; redi[rg][i][wid2] = idx; }
    }
    if (tid == 0) anytie = 0;
    if (tid < 32) rownc[tid] = 0;
    __syncthreads();
    if (tid < 32) {
        float v0 = red[tid >> 3][tid & 7][0]; int i0 = redi[tid >> 3][tid & 7][0];
        float v1 = red[tid >> 3][tid & 7][1]; int i1 = redi[tid >> 3][tid & 7][1];
        if (v1 < v0 || (v1 == v0 && i1 < i0)) { v0 = v1; i0 = i1; }
        rowmin[tid] = v0; rowcode[tid] = i0;
    }
    __syncthreads();

    // ---------------- near-tie candidates (1e-3 band >> fp32 dist error) --------
    #pragma unroll
    for (int i = 0; i < 8; ++i) {
        int r = base_r + i;
        float thr = rowmin[r] + 1e-3f;
        #pragma unroll
        for (int j = 0; j < 8; ++j) {
            if (acc[i][j] <= thr) {
                int slot = atomicAdd(&rownc[r], 1);
                if (slot < 8) rowcand[r][slot] = c + 128 * j;
            }
        }
    }
    __syncthreads();
    if (tid < 32 && rownc[tid] > 1) atomicAdd(&anytie, 1);
    __syncthreads();
    if (anytie) {    // rare path: fp64 re-dot, numpy-style fp32 final rounding
        for (int r = 0; r < 32; ++r) {
            int nc = rownc[r];
            if (nc <= 1) continue;
            int lim = nc < 8 ? nc : 8;
            int n = rowBase + r;
            float zzn = ws[WS_ZZ + n];
            float bestd = 0.f; int bestk = -1;
            for (int ci = 0; ci < lim; ++ci) {
                int kc = rowcand[r][ci];
                double part = 0.0;
                if (tid < 256)
                    part = (double)z[(size_t)n * DIM + tid] * (double)embed[(size_t)kc * DIM + tid];
                #pragma unroll
                for (int off = 32; off; off >>= 1) part += __shfl_down(part, off, 64);
                if (lane == 0) sdd[wid] = part;
                __syncthreads();
                double dot = 0.0;
                for (int w = 0; w < 8; ++w) dot += sdd[w];
                float d32 = (zzn - 2.0f * (float)dot) + ws[WS_EE + kc];
                if (bestk < 0 || d32 < bestd || (d32 == bestd && kc < bestk)) { bestd = d32; bestk = kc; }
                __syncthreads();     // protect sdd reuse
            }
            if (tid == 0) rowcode[r] = bestk;
        }
        __syncthreads();
    }

    // ---------------- softmax (shift by rowmin is exact-invariant) --------------
    #pragma unroll
    for (int i = 0; i < 8; ++i) {
        float m = rowmin[base_r + i];
        float s = 0.f;
        #pragma unroll
        for (int j = 0; j < 8; ++j) {
            acc[i][j] = __expf((m - acc[i][j]) * 10.0f);
            s += acc[i][j];
        }
        #pragma unroll
        for (int off = 32; off; off >>= 1) s += __shfl_down(s, off, 64);
        if (lane == 0) red[rg][i][wid2] = s;
    }
    __syncthreads();
    if (tid < 32) rowsum[tid] = red[tid >> 3][tid & 7][0] + red[tid >> 3][tid & 7][1];
    __syncthreads();
    #pragma unroll
    for (int i = 0; i < 8; ++i) {
        int n = rowBase + base_r + i;
        float inv = 1.0f / rowsum[base_r + i];
        float* orow = out + OFF_SOFT + (size_t)n * K_CODES;
        #pragma unroll
        for (int j = 0; j < 8; ++j) orow[c + 128 * j] = acc[i][j] * inv;  // lane-coalesced
    }

    // ---------------- z_q, commitment loss, EMA scatter -------------------------
    {
        int r   = tid >> 4;          // 0..31
        int seg = tid & 15;          // 16 threads/row, 16 d each
        int n = rowBase + r;
        int code = rowcode[r];
        int dd = seg * 16;
        float lsum = 0.f;
        #pragma unroll
        for (int q = 0; q < 4; ++q) {
            float4 e4 = *(const float4*)&embed[(size_t)code * DIM + dd + q * 4];
            float4 z4 = *(const float4*)&z[(size_t)n * DIM + dd + q * 4];
            *(float4*)&out[OFF_ZQ + (size_t)n * DIM + dd + q * 4] = e4;
            float dx = z4.x - e4.x, dy = z4.y - e4.y, dz_ = z4.z - e4.z, dw = z4.w - e4.w;
            lsum += dx * dx + dy * dy + dz_ * dz_ + dw * dw;
            atomicAdd(&ws[WS_ESUM + (size_t)code * DIM + dd + q * 4 + 0], z4.x);
            atomicAdd(&ws[WS_ESUM + (size_t)code * DIM + dd + q * 4 + 1], z4.y);
            atomicAdd(&ws[WS_ESUM + (size_t)code * DIM + dd + q * 4 + 2], z4.z);
            atomicAdd(&ws[WS_ESUM + (size_t)code * DIM + dd + q * 4 + 3], z4.w);
        }
        #pragma unroll
        for (int off = 8; off; off >>= 1) lsum += __shfl_down(lsum, off, 16);
        if (seg == 0) {
            atomicAdd(&ws[WS_LOSS + (n & 1023)], lsum);   // 1024-way distributed
            atomicAdd(&ws[WS_COUNTS + code], 1.0f);
            out[OFF_CODES + n] = (float)code;
        }
    }
}

__global__ __launch_bounds__(1024) void k4a_stats(const float* __restrict__ cluster_size,
                                                  float* __restrict__ ws,
                                                  float* __restrict__ out) {
    __shared__ float sm[16];
    int k = threadIdx.x;
    int lane = k & 63, wave = k >> 6;
    float cnt = ws[WS_COUNTS + k];
    float ncs = 0.99f * cluster_size[k] + 0.01f * cnt;
    out[OFF_NCS + k] = ncs;

    // nsum
    float v = ncs;
    #pragma unroll
    for (int off = 32; off; off >>= 1) v += __shfl_down(v, off, 64);
    if (lane == 0) sm[wave] = v;
    __syncthreads();
    if (k == 0) {
        float t = 0.f;
        for (int w = 0; w < 16; ++w) t += sm[w];
        ws[WS_NSUM] = t;
    }
    __syncthreads();

    // entropy
    float avg = cnt / (float)N_ROWS;
    v = -avg * logf(avg + 1e-10f);
    #pragma unroll
    for (int off = 32; off; off >>= 1) v += __shfl_down(v, off, 64);
    if (lane == 0) sm[wave] = v;
    __syncthreads();
    if (k == 0) {
        float ent = 0.f;
        for (int w = 0; w < 16; ++w) ent += sm[w];
        out[OFF_ENT]  = ent;
        out[OFF_PERP] = expf(ent);
    }
    __syncthreads();

    // loss: sum the 1024 distributed slots
    v = ws[WS_LOSS + k];
    #pragma unroll
    for (int off = 32; off; off >>= 1) v += __shfl_down(v, off, 64);
    if (lane == 0) sm[wave] = v;
    __syncthreads();
    if (k == 0) {
        float t = 0.f;
        for (int w = 0; w < 16; ++w) t += sm[w];
        out[OFF_LOSS] = t / 8388608.0f;
    }
}

__global__ __launch_bounds__(256) void k4b_embed(const float* __restrict__ embed_avg,
                                                 const float* __restrict__ ws,
                                                 float* __restrict__ out) {
    int k = blockIdx.x, d = threadIdx.x;
    float es  = ws[WS_ESUM + (size_t)k * DIM + d];
    float nea = 0.99f * embed_avg[(size_t)k * DIM + d] + 0.01f * es;
    out[OFF_NEA + (size_t)k * DIM + d] = nea;
    float ncs  = out[OFF_NCS + k];
    float nsum = ws[WS_NSUM];
    float csn  = (ncs + 1e-5f) / (nsum + K_CODES * 1e-5f) * nsum;
    out[OFF_NEMB + (size_t)k * DIM + d] = nea / csn;
}

extern "C" void kernel_launch(void* const* d_in, const int* in_sizes, int n_in,
                              void* d_out, int out_size, void* d_ws, size_t ws_size,
                              hipStream_t stream) {
    const float* z            = (const float*)d_in[0];
    const float* embed        = (const float*)d_in[1];
    const float* cluster_size = (const float*)d_in[2];
    const float* embed_avg    = (const float*)d_in[3];
    float* out = (float*)d_out;
    float* ws  = (float*)d_ws;

    k0_zero<<<(WS_TOTAL + 255) / 256, 256, 0, stream>>>(ws);
    k1_norms<<<(N_ROWS + K_CODES) / 4, 256, 0, stream>>>(z, embed, ws);
    k23_fused<<<N_ROWS / 32, 512, 0, stream>>>(z, embed, ws, out);
    k4a_stats<<<1, 1024, 0, stream>>>(cluster_size, ws, out);
    k4b_embed<<<K_CODES, 256, 0, stream>>>(embed_avg, ws, out);
}